// Round 6
// baseline (103.939 us; speedup 1.0000x reference)
//
#include <hip/hip_runtime.h>
#include <hip/hip_bf16.h>

#define BB 16
#define LL 2048
#define DD 64

typedef __attribute__((ext_vector_type(8))) short short8t;
typedef __attribute__((ext_vector_type(4))) float f32x4;
typedef __attribute__((ext_vector_type(4))) unsigned short ushort4t;

__device__ __forceinline__ unsigned short f2bf(float x) {
  union { float f; unsigned int u; } c; c.f = x;
  unsigned int u = c.u;
  u += 0x7fffu + ((u >> 16) & 1u);   // RNE; inputs are finite
  return (unsigned short)(u >> 16);
}

// merged prep: blocks 0..2047 cvt Q, 2048..4095 cvt K, 4096..4607 vtrans V
__global__ void prep(const float* __restrict__ q, const float* __restrict__ k,
                     const float* __restrict__ v,
                     unsigned short* __restrict__ Qb, unsigned short* __restrict__ Kb,
                     unsigned short* __restrict__ VT) {
  __shared__ unsigned short t[64][66];
  int bid = blockIdx.x;
  if (bid < 4096) {
    const float* in = (bid < 2048) ? q : k;
    unsigned short* outp = (bid < 2048) ? Qb : Kb;
    int i = (bid & 2047) * 1024 + threadIdx.x * 4;
    float4 v4 = *(const float4*)(in + i);
    ushort4t o;
    o.x = f2bf(v4.x); o.y = f2bf(v4.y); o.z = f2bf(v4.z); o.w = f2bf(v4.w);
    *(ushort4t*)(outp + i) = o;
  } else {
    int vb = bid - 4096;
    int b = vb >> 5, j0 = (vb & 31) * 64;
    const float* src = v + ((size_t)b * LL + j0) * DD;
#pragma unroll
    for (int i = 0; i < 16; ++i) {
      int lin = i * 256 + threadIdx.x;
      int j = lin >> 6, d = lin & 63;
      t[j][d] = f2bf(src[lin]);
    }
    __syncthreads();
    unsigned short* dst = VT + (size_t)b * DD * LL;
#pragma unroll
    for (int i = 0; i < 16; ++i) {
      int lin = i * 256 + threadIdx.x;
      int d = lin >> 6, j = lin & 63;
      dst[(size_t)d * LL + j0 + j] = t[j][d];
    }
  }
}

__device__ __forceinline__ void async_cp16(const unsigned short* src, unsigned short* dst_lds) {
  __builtin_amdgcn_global_load_lds(
      (const __attribute__((address_space(1))) unsigned int*)src,
      (__attribute__((address_space(3))) unsigned int*)dst_lds, 16, 0, 0);
}

// Row-ownership decomposition: 4 waves/block, wave w owns q-rows q0+16w..+15 and
// walks ALL k in 16 steps of BK=128 -> each row's attn advances 512B contiguous per
// step (sequential HBM write streams). K dbuf (32KB) + V single (16KB, fenced) shared;
// PF f32 [16][128] per wave (32KB). 80KB LDS -> 2 blocks/CU.
__global__ void __launch_bounds__(256, 2)
attn_main(const unsigned short* __restrict__ Qb, const unsigned short* __restrict__ Kb,
          const unsigned short* __restrict__ VTb, const int* __restrict__ mask,
          float* __restrict__ out, float* __restrict__ attn) {
  __shared__ __align__(16) unsigned short TB[40960];  // 80 KB

  const int tid = threadIdx.x;
  const int w = tid >> 6;
  const int l = tid & 63;
  const int l15 = l & 15;
  const int g = l >> 4;

  // XCD-bijective swizzle (512 % 8 == 0): each XCD owns 2 whole batches.
  const int swzb = (blockIdx.x & 7) * 64 + (blockIdx.x >> 3);
  const int b = swzb >> 5;
  const int q0 = (swzb & 31) << 6;

  unsigned short* KT0 = TB;              // [128][64] bf16
  unsigned short* KT1 = TB + 8192;
  unsigned short* VTt = TB + 16384;      // [64][128] bf16 (d-major)
  float* PFw = (float*)(TB + 24576) + w * 2048;  // [16][128] f32 per wave

  const unsigned short* Kbb = Kb + (size_t)b * LL * DD;
  const unsigned short* VTbb = VTb + (size_t)b * DD * LL;
  const int* maskb = mask + b * LL;

  auto stageK = [&](int t, unsigned short* KB) {  // block-cooperative, 16KB
    int k0 = (t & 15) * 128;
    const unsigned short* gs = Kbb + (size_t)k0 * DD;
#pragma unroll
    for (int i2 = 0; i2 < 4; ++i2) {
      int row = i2 * 32 + w * 8 + (l >> 3);
      int ce = ((l & 7) * 8) ^ ((row & 3) << 4);
      async_cp16(gs + row * 64 + ce, KB + (i2 * 32 + w * 8) * 64);
    }
  };
  auto stageV = [&](int t) {
    int k0 = (t & 15) * 128;
#pragma unroll
    for (int i2 = 0; i2 < 4; ++i2) {
      int row = i2 * 16 + w * 4 + (l >> 4);
      int ce = ((l & 15) * 8) ^ ((row & 3) << 4);
      async_cp16(VTbb + (size_t)row * LL + k0 + ce, VTt + (i2 * 16 + w * 4) * 128);
    }
  };
  auto loadMask = [&](int t, int* mk) {
    int k0 = (t & 15) * 128;
#pragma unroll
    for (int ni = 0; ni < 8; ++ni) mk[ni] = maskb[k0 + 16 * ni + l15];
  };

  // persistent Q fragments for this wave's 16 rows: row = q0+16w+l15, d = 32h+8g+e
  short8t qf[2];
  {
    const unsigned short* qbase = Qb + ((size_t)b * LL + q0 + 16 * w + l15) * DD + 8 * g;
    qf[0] = *(const short8t*)(qbase);
    qf[1] = *(const short8t*)(qbase + 32);
  }

  float ls[4] = {0.f, 0.f, 0.f, 0.f};
  int mkA[8], mkB[8];

  // ---------------- pass A: row sums of exp(s) ----------------
  auto stepA = [&](int t, const unsigned short* KBc, unsigned short* KBn,
                   const int* mkc, int* mkn) {
    asm volatile("s_waitcnt vmcnt(0)" ::: "memory");
    __syncthreads();  // K[t] resident for all waves
    loadMask(t + 1, mkn);
    stageK(t + 1, KBn);
    __builtin_amdgcn_sched_barrier(0);
    short8t kf[8][2];
#pragma unroll
    for (int ni = 0; ni < 8; ++ni)
#pragma unroll
      for (int h = 0; h < 2; ++h)
        kf[ni][h] = *(const short8t*)(KBc + (16 * ni + l15) * 64 + ((32 * h + 8 * g) ^ ((l15 & 3) << 4)));
    f32x4 sacc[8] = {};
    __builtin_amdgcn_s_setprio(1);
#pragma unroll
    for (int ni = 0; ni < 8; ++ni)
#pragma unroll
      for (int h = 0; h < 2; ++h)
        sacc[ni] = __builtin_amdgcn_mfma_f32_16x16x32_bf16(qf[h], kf[ni][h], sacc[ni], 0, 0, 0);
    __builtin_amdgcn_s_setprio(0);
#pragma unroll
    for (int ni = 0; ni < 8; ++ni) {
      int mk = mkc[ni];
#pragma unroll
      for (int r = 0; r < 4; ++r)
        ls[r] += mk ? 0.f : __expf(sacc[ni][r] * 0.125f);
    }
  };

  stageK(0, KT0);
  loadMask(0, mkA);
  for (int jj = 0; jj < 8; ++jj) {
    stepA(2 * jj, KT0, KT1, mkA, mkB);
    stepA(2 * jj + 1, KT1, KT0, mkB, mkA);
  }
  // pass A tail staged K(0) into KT0 and mask(0) into mkA for pass B.

  // row sums are wave-local: reduce across l15 within each g-group
  float rinv_[4];
#pragma unroll
  for (int r = 0; r < 4; ++r) {
    float s = ls[r];
    s += __shfl_xor(s, 1);
    s += __shfl_xor(s, 2);
    s += __shfl_xor(s, 4);
    s += __shfl_xor(s, 8);
    rinv_[r] = 1.0f / s;
  }

  // ---------------- pass B: recompute S, write attn (sequential rows), O = P*V ----------------
  f32x4 oacc[4] = {};
  const size_t abase0 = (size_t)(b * LL + q0 + 16 * w) * LL;

  auto stepB = [&](int t, bool first, const unsigned short* KBc, unsigned short* KBn,
                   const int* mkc, int* mkn) {
    // drain prev prefetch (16 ops) but keep prev 8 attn stores in flight
    if (first) { asm volatile("s_waitcnt vmcnt(0)" ::: "memory"); }
    else       { asm volatile("s_waitcnt vmcnt(8)" ::: "memory"); }
    __syncthreads();  // barrier1: K[t], V[t] resident
    const int k0 = (t & 15) * 128;

    // V fragments must be register-resident before V restage (single buffer)
    short8t vf[4][4];
#pragma unroll
    for (int kk = 0; kk < 4; ++kk)
#pragma unroll
      for (int ni = 0; ni < 4; ++ni)
        vf[kk][ni] = *(const short8t*)(VTt + (16 * ni + l15) * 128 + ((32 * kk + 8 * g) ^ ((l15 & 3) << 4)));
    asm volatile("s_waitcnt lgkmcnt(0)" ::: "memory");
    __builtin_amdgcn_sched_barrier(0);
    __syncthreads();  // barrier2: all waves done reading V[t]

    loadMask(t + 1, mkn);
    stageK(t + 1, KBn);
    stageV(t + 1);
    __builtin_amdgcn_sched_barrier(0);

    short8t kf[8][2];
#pragma unroll
    for (int ni = 0; ni < 8; ++ni)
#pragma unroll
      for (int h = 0; h < 2; ++h)
        kf[ni][h] = *(const short8t*)(KBc + (16 * ni + l15) * 64 + ((32 * h + 8 * g) ^ ((l15 & 3) << 4)));
    f32x4 sacc[8] = {};
    __builtin_amdgcn_s_setprio(1);
#pragma unroll
    for (int ni = 0; ni < 8; ++ni)
#pragma unroll
      for (int h = 0; h < 2; ++h)
        sacc[ni] = __builtin_amdgcn_mfma_f32_16x16x32_bf16(qf[h], kf[ni][h], sacc[ni], 0, 0, 0);
    __builtin_amdgcn_s_setprio(0);

    // P -> per-wave f32 tile (2-way bank aliasing = free)
#pragma unroll
    for (int ni = 0; ni < 8; ++ni) {
      int mk = mkc[ni];
#pragma unroll
      for (int r = 0; r < 4; ++r) {
        float p = mk ? 0.f : __expf(sacc[ni][r] * 0.125f) * rinv_[r];
        PFw[(4 * g + r) * 128 + ((16 * ni + l15) ^ ((g & 1) << 4))] = p;
      }
    }
    asm volatile("s_waitcnt lgkmcnt(0)" ::: "memory");
    __builtin_amdgcn_sched_barrier(0);

    // attn burst: each of 16 rows gets 512B contiguous this step (float4 stores)
#pragma unroll
    for (int it = 0; it < 8; ++it) {
      int row = l >> 2;
      int cb = (l & 3) * 4 + 16 * it;
      f32x4 pv = *(const f32x4*)(PFw + row * 128 + (cb ^ (((row >> 2) & 1) << 4)));
      *(f32x4*)(attn + abase0 + (size_t)row * LL + k0 + cb) = pv;
    }

    // PV fragments from PF (f32 -> bf16 in regs)
    short8t pfr[4];
#pragma unroll
    for (int kk = 0; kk < 4; ++kk) {
      const float* src = PFw + l15 * 128 + ((32 * kk + 8 * g) ^ (((l15 >> 2) & 1) << 4));
      f32x4 pa = *(const f32x4*)(src);
      f32x4 pb = *(const f32x4*)(src + 4);
      short8t f;
      f[0] = (short)f2bf(pa[0]); f[1] = (short)f2bf(pa[1]);
      f[2] = (short)f2bf(pa[2]); f[3] = (short)f2bf(pa[3]);
      f[4] = (short)f2bf(pb[0]); f[5] = (short)f2bf(pb[1]);
      f[6] = (short)f2bf(pb[2]); f[7] = (short)f2bf(pb[3]);
      pfr[kk] = f;
    }
    __builtin_amdgcn_s_setprio(1);
#pragma unroll
    for (int kk = 0; kk < 4; ++kk)
#pragma unroll
      for (int ni = 0; ni < 4; ++ni)
        oacc[ni] = __builtin_amdgcn_mfma_f32_16x16x32_bf16(pfr[kk], vf[kk][ni], oacc[ni], 0, 0, 0);
    __builtin_amdgcn_s_setprio(0);
  };

  stageV(0);
  stepB(0, true, KT0, KT1, mkA, mkB);
  for (int jj = 0; jj < 7; ++jj) {
    stepB(2 * jj + 1, false, KT1, KT0, mkB, mkA);
    stepB(2 * jj + 2, false, KT0, KT1, mkA, mkB);
  }
  stepB(15, false, KT1, KT0, mkB, mkA);

  // drain tail prefetch glds before kernel end (LDS writes must not dangle)
  asm volatile("s_waitcnt vmcnt(0)" ::: "memory");

  // epilogue: out from regs (wave owns its rows; no cross-wave reduce)
#pragma unroll
  for (int ni = 0; ni < 4; ++ni)
#pragma unroll
    for (int r = 0; r < 4; ++r)
      out[(size_t)(b * LL + q0 + 16 * w + 4 * g + r) * DD + 16 * ni + l15] = oacc[ni][r];
}

extern "C" void kernel_launch(void* const* d_in, const int* in_sizes, int n_in,
                              void* d_out, int out_size, void* d_ws, size_t ws_size,
                              hipStream_t stream) {
  const float* q = (const float*)d_in[0];
  const float* k = (const float*)d_in[1];
  const float* v = (const float*)d_in[2];
  const int* pm = (const int*)d_in[3];

  float* out = (float*)d_out;
  float* attn = out + (size_t)BB * LL * DD;

  unsigned short* Qb = (unsigned short*)d_ws;
  unsigned short* Kb = Qb + (size_t)BB * LL * DD;
  unsigned short* VT = Kb + (size_t)BB * LL * DD;

  prep<<<4608, 256, 0, stream>>>(q, k, v, Qb, Kb, VT);
  attn_main<<<512, 256, 0, stream>>>(Qb, Kb, VT, pm, out, attn);
}